// Round 7
// baseline (300.093 us; speedup 1.0000x reference)
//
#include <hip/hip_runtime.h>

// GCN autoencoder: N=50000, E=800000, 128 -> 16 -> 128.
// Round 7: R6 structure (radix-bucket + LDS fp32 accumulate) with the gather
// loops rebuilt for memory-level parallelism:
//  - 1024 buckets x 49 nodes, 512-thread blocks, __launch_bounds__(512,8)
//    -> up to 32 waves/CU (R6: 16, occupancy 40%).
//  - edge loop unrolled x4, load-batch then commit-batch: 4 arr reads + 4
//    feature gathers in flight per wave before the ds_add commits
//    (R6 had ~1 gather in flight -> HBM-latency bound at 6% BW, 80 us).

#define N_NODES 50000
#define N_EDGES 800000
#define D_IN    128
#define D_H     16
#define K_BUCK  1024
#define NPB2    49       // nodes per bucket: bucket = dst / 49 (max 49999/49 = 1020)
#define BSHIFT  10
#define BCAP    (1 << BSHIFT)   // 1024 slots; mean 781, sd 28 -> 8.7 sigma margin
#define PA_BLKS 256
#define PA_CHUNK 3125    // 800000/256
#define H1_BLKS 3125     // 50000*16/256
#define GC_PAD  16       // gcur stride in ints (64 B line padding)

// ---- K1: fused [phase A bucket scatter (blocks 0..255)] + [h1 GEMM] ----
__global__ __launch_bounds__(256) void k1_fused(
        const int* __restrict__ src, const int* __restrict__ dst,
        const float* __restrict__ x, const float* __restrict__ W1,
        int* __restrict__ gcur, float* __restrict__ h1, int* __restrict__ arr) {
    __shared__ float w1s[D_IN * D_H];   // GEMM segment
    __shared__ int hist[K_BUCK];        // phase A segment
    __shared__ int cur[K_BUCK];
    int bid = blockIdx.x;
    int tid = threadIdx.x;

    if (bid < PA_BLKS) {
        // ---- phase A: bucket scatter of packed (src<<6 | local_dst) ----
        int e0 = bid * PA_CHUNK;
        for (int b = tid; b < K_BUCK; b += 256) hist[b] = 0;
        __syncthreads();
        for (int i = tid; i < PA_CHUNK; i += 256) {
            int d = dst[e0 + i];
            atomicAdd(&hist[d / NPB2], 1);
        }
        __syncthreads();
        for (int b = tid; b < K_BUCK; b += 256)
            cur[b] = (b << BSHIFT) + atomicAdd(&gcur[b * GC_PAD], hist[b]);
        __syncthreads();
        for (int i = tid; i < PA_CHUNK; i += 256) {
            int d = dst[e0 + i];
            int s = src[e0 + i];
            int b = d / NPB2;
            int pos = atomicAdd(&cur[b], 1);
            if (pos < ((b + 1) << BSHIFT))       // overflow guard (8.7 sigma)
                arr[pos] = (s << 6) | (d - b * NPB2);
        }
    } else {
        // ---- h1 = x @ W1 ----
        for (int i = tid; i < D_IN * D_H; i += 256) w1s[i] = W1[i];
        __syncthreads();
        int idx = (bid - PA_BLKS) * 256 + tid;   // < 800000 exactly
        int row = idx >> 4;
        int col = idx & 15;
        const float4* xr = (const float4*)(x + row * D_IN);
        float acc = 0.0f;
        #pragma unroll
        for (int k4 = 0; k4 < D_IN / 4; ++k4) {
            float4 v = xr[k4];
            acc += v.x * w1s[(k4 * 4 + 0) * D_H + col];
            acc += v.y * w1s[(k4 * 4 + 1) * D_H + col];
            acc += v.z * w1s[(k4 * 4 + 2) * D_H + col];
            acc += v.w * w1s[(k4 * 4 + 3) * D_H + col];
        }
        h1[idx] = acc;
    }
}

// ---- K2: per-bucket degree -> dinv, then scale h1 -> h1s = h1*dinv in place ----
__global__ __launch_bounds__(256) void k2_deg_scale(
        const int* __restrict__ arr, const int* __restrict__ gcur,
        float* __restrict__ h1, float* __restrict__ dinv) {
    __shared__ int cnt[NPB2];
    __shared__ float sdi[NPB2];
    int k = blockIdx.x, tid = threadIdx.x;
    for (int i = tid; i < NPB2; i += 256) cnt[i] = 0;
    __syncthreads();
    int count = min(gcur[k * GC_PAD], BCAP);
    int base = k << BSHIFT;
    for (int i = tid; i < count; i += 256) atomicAdd(&cnt[arr[base + i] & 63], 1);
    __syncthreads();
    int n0 = k * NPB2;
    int ncnt = min(NPB2, N_NODES - n0);
    for (int i = tid; i < ncnt; i += 256) {
        float di = rsqrtf((float)cnt[i] + 1.0f);   // +1 = self loop
        sdi[i] = di;
        dinv[n0 + i] = di;
    }
    __syncthreads();
    for (int g = tid; g < ncnt * 4; g += 256) {    // float4 groups
        int i = g >> 2;
        float di = sdi[i];
        float4* p = (float4*)(h1 + (n0 + i) * D_H);
        float4 v = p[g & 3];
        v.x *= di; v.y *= di; v.z *= di; v.w *= di;
        p[g & 3] = v;
    }
}

// edge-accumulate into LDS acc, unrolled x4 for MLP
__device__ __forceinline__ void edge_accum(
        const float* __restrict__ feat_s, const int* __restrict__ arr,
        int base, int count, int ch, int i0, float* acc) {
    int i = i0;
    for (; i + 96 < count; i += 128) {            // 4 groups of 32 i-slots
        int p0 = arr[base + i];
        int p1 = arr[base + i + 32];
        int p2 = arr[base + i + 64];
        int p3 = arr[base + i + 96];
        float v0 = feat_s[(p0 >> 6) * D_H + ch];
        float v1 = feat_s[(p1 >> 6) * D_H + ch];
        float v2 = feat_s[(p2 >> 6) * D_H + ch];
        float v3 = feat_s[(p3 >> 6) * D_H + ch];
        atomicAdd(&acc[(p0 & 63) * D_H + ch], v0);
        atomicAdd(&acc[(p1 & 63) * D_H + ch], v1);
        atomicAdd(&acc[(p2 & 63) * D_H + ch], v2);
        atomicAdd(&acc[(p3 & 63) * D_H + ch], v3);
    }
    for (; i < count; i += 32) {
        int p = arr[base + i];
        atomicAdd(&acc[(p & 63) * D_H + ch], feat_s[(p >> 6) * D_H + ch]);
    }
}

// ---- K3: encoder aggregation: zs[i] = di*( di*(h1s_self + S h1s[s]) + b1 ) ----
__global__ __launch_bounds__(512, 8) void k3_agg_enc(
        const float* __restrict__ feat_s, const int* __restrict__ arr,
        const int* __restrict__ gcur, const float* __restrict__ dinv,
        const float* __restrict__ b1, float* __restrict__ zs) {
    __shared__ float acc[NPB2 * D_H];   // 3.1 KB
    int k = blockIdx.x, tid = threadIdx.x;
    for (int i = tid; i < NPB2 * D_H; i += 512) acc[i] = 0.0f;
    __syncthreads();
    int count = min(gcur[k * GC_PAD], BCAP);
    int base = k << BSHIFT;
    edge_accum(feat_s, arr, base, count, tid & 15, tid >> 4, acc);
    __syncthreads();
    int n0 = k * NPB2;
    int ncnt = min(NPB2, N_NODES - n0);
    for (int idx = tid; idx < ncnt * D_H; idx += 512) {
        int i = n0 + (idx >> 4);
        int c = idx & 15;
        float di = dinv[i];
        float tot = acc[idx] + feat_s[i * D_H + c];
        zs[i * D_H + c] = di * (di * tot + b1[c]);  // z*dinv, pre-scaled for decoder
    }
}

// ---- K4: decoder aggregation fused with W2 GEMM + b2; writes out directly ----
__global__ __launch_bounds__(512, 8) void k4_agg_dec_out(
        const float* __restrict__ zs, const int* __restrict__ arr,
        const int* __restrict__ gcur, const float* __restrict__ dinv,
        const float* __restrict__ W2, const float* __restrict__ b2,
        float* __restrict__ out) {
    __shared__ float acc[NPB2 * D_H];   // 3.1 KB
    __shared__ float w2s[D_H * D_IN];   // 8 KB
    int k = blockIdx.x, tid = threadIdx.x;
    for (int i = tid; i < NPB2 * D_H; i += 512) acc[i] = 0.0f;
    for (int i = tid; i < D_H * D_IN; i += 512) w2s[i] = W2[i];
    __syncthreads();
    int count = min(gcur[k * GC_PAD], BCAP);
    int base = k << BSHIFT;
    edge_accum(zs, arr, base, count, tid & 15, tid >> 4, acc);
    __syncthreads();
    int n0 = k * NPB2;
    int ncnt = min(NPB2, N_NODES - n0);
    // agg2 in place: acc = di*(acc + zs_self)
    for (int idx = tid; idx < ncnt * D_H; idx += 512) {
        int i = n0 + (idx >> 4);
        float di = dinv[i];
        acc[idx] = di * (acc[idx] + zs[i * D_H + (idx & 15)]);
    }
    __syncthreads();
    // out[n][j] = sum_c acc[n][c]*W2[c][j] + b2[j]
    for (int idx = tid; idx < ncnt * D_IN; idx += 512) {
        int n = idx >> 7;
        int j = idx & 127;
        const float* a = &acc[n * D_H];
        float v = b2[j];
        #pragma unroll
        for (int c = 0; c < D_H; ++c) v += a[c] * w2s[c * D_IN + j];
        out[(n0 + n) * D_IN + j] = v;
    }
}

extern "C" void kernel_launch(void* const* d_in, const int* in_sizes, int n_in,
                              void* d_out, int out_size, void* d_ws, size_t ws_size,
                              hipStream_t stream) {
    const float* x  = (const float*)d_in[0];
    const int*   ei = (const int*)d_in[1];   // [2, E]: src then dst
    const float* W1 = (const float*)d_in[2];
    const float* b1 = (const float*)d_in[3];
    const float* W2 = (const float*)d_in[4];
    const float* b2 = (const float*)d_in[5];
    float* out = (float*)d_out;

    const int* src = ei;
    const int* dst = ei + N_EDGES;

    // ws carve: gcur[1024*16] | dinv[N] | h1[N*16] | zs[N*16] | arr[1024*1024]  (~10.8 MB)
    char* base = (char*)d_ws;
    int*   gcur = (int*)base;                  base += K_BUCK * GC_PAD * 4;
    float* dinv = (float*)base;                base += N_NODES * 4;
    float* h1   = (float*)base;                base += N_NODES * D_H * 4;
    float* zs   = (float*)base;                base += N_NODES * D_H * 4;
    int*   arr  = (int*)base;                  base += K_BUCK * BCAP * 4;

    hipMemsetAsync(gcur, 0, K_BUCK * GC_PAD * sizeof(int), stream);

    k1_fused<<<PA_BLKS + H1_BLKS, 256, 0, stream>>>(src, dst, x, W1, gcur, h1, arr);
    k2_deg_scale<<<K_BUCK, 256, 0, stream>>>(arr, gcur, h1, dinv);
    k3_agg_enc<<<K_BUCK, 512, 0, stream>>>(h1, arr, gcur, dinv, b1, zs);
    k4_agg_dec_out<<<K_BUCK, 512, 0, stream>>>(zs, arr, gcur, dinv, W2, b2, out);
}

// Round 8
// 257.004 us; speedup vs baseline: 1.1677x; 1.1677x over previous
//
#include <hip/hip_runtime.h>

// GCN autoencoder: N=50000, E=800000, 128 -> 16 -> 128.
// Round 8: R6 structure (radix-bucket + LDS fp32 accumulate), fixed per R7 lessons:
//  - LDS atomics written DIRECTLY on the __shared__ array in kernel scope
//    (R7 laundered them through a generic float* helper -> 112+112 MB of
//    mystery symmetric HBM traffic and a 1.5x regression).
//  - 512 buckets x 98 nodes (R6's 256 buckets = exactly 1 block/CU).
//  - gather loop unrolled x4 in-kernel: 4 arr reads + 4 feature gathers in
//    flight before the 4 ds_add commits.
//  - k4 epilogue GEMM in float4: R6 did 784 scalar ds_read_b32/thread (~30 us,
//    the real k4 bottleneck per cycle math).

#define N_NODES 50000
#define N_EDGES 800000
#define D_IN    128
#define D_H     16
#define K_BUCK  512
#define NPB2    98       // nodes per bucket: bucket = dst / 98 (max 49999/98 = 510)
#define BSHIFT  11
#define BCAP    (1 << BSHIFT)   // 2048 slots; mean 1562, sd 40 -> 12 sigma margin
#define PA_BLKS 256
#define PA_CHUNK 3125    // 800000/256
#define GC_PAD  16       // gcur stride in ints (64 B line padding)

// ---- K1: fused [phase A bucket scatter (blocks 0..255)] + [h1 GEMM] ----
__global__ __launch_bounds__(256) void k1_fused(
        const int* __restrict__ src, const int* __restrict__ dst,
        const float* __restrict__ x, const float* __restrict__ W1,
        int* __restrict__ gcur, float* __restrict__ h1, int* __restrict__ arr) {
    __shared__ float w1s[D_IN * D_H];   // GEMM segment (8 KB)
    __shared__ int hist[K_BUCK];        // phase A segment (2+2 KB)
    __shared__ int cur[K_BUCK];
    int bid = blockIdx.x;
    int tid = threadIdx.x;

    if (bid < PA_BLKS) {
        // ---- phase A: bucket scatter of packed (src<<7 | local_dst) ----
        int e0 = bid * PA_CHUNK;
        for (int b = tid; b < K_BUCK; b += 256) hist[b] = 0;
        __syncthreads();
        for (int i = tid; i < PA_CHUNK; i += 256) {
            int d = dst[e0 + i];
            atomicAdd(&hist[d / NPB2], 1);
        }
        __syncthreads();
        for (int b = tid; b < K_BUCK; b += 256)
            cur[b] = (b << BSHIFT) + atomicAdd(&gcur[b * GC_PAD], hist[b]);
        __syncthreads();
        for (int i = tid; i < PA_CHUNK; i += 256) {
            int d = dst[e0 + i];
            int s = src[e0 + i];
            int b = d / NPB2;
            int pos = atomicAdd(&cur[b], 1);
            if (pos < ((b + 1) << BSHIFT))       // overflow guard (12 sigma)
                arr[pos] = (s << 7) | (d - b * NPB2);
        }
    } else {
        // ---- h1 = x @ W1 ----
        for (int i = tid; i < D_IN * D_H; i += 256) w1s[i] = W1[i];
        __syncthreads();
        int idx = (bid - PA_BLKS) * 256 + tid;   // < 800000 exactly
        int row = idx >> 4;
        int col = idx & 15;
        const float4* xr = (const float4*)(x + row * D_IN);
        float acc = 0.0f;
        #pragma unroll
        for (int k4 = 0; k4 < D_IN / 4; ++k4) {
            float4 v = xr[k4];
            acc += v.x * w1s[(k4 * 4 + 0) * D_H + col];
            acc += v.y * w1s[(k4 * 4 + 1) * D_H + col];
            acc += v.z * w1s[(k4 * 4 + 2) * D_H + col];
            acc += v.w * w1s[(k4 * 4 + 3) * D_H + col];
        }
        h1[idx] = acc;
    }
}

// ---- K2: per-bucket degree -> dinv, then scale h1 -> h1s = h1*dinv in place ----
__global__ __launch_bounds__(256) void k2_deg_scale(
        const int* __restrict__ arr, const int* __restrict__ gcur,
        float* __restrict__ h1, float* __restrict__ dinv) {
    __shared__ int cnt[NPB2];
    __shared__ float sdi[NPB2];
    int k = blockIdx.x, tid = threadIdx.x;
    for (int i = tid; i < NPB2; i += 256) cnt[i] = 0;
    __syncthreads();
    int count = min(gcur[k * GC_PAD], BCAP);
    int base = k << BSHIFT;
    for (int i = tid; i < count; i += 256) atomicAdd(&cnt[arr[base + i] & 127], 1);
    __syncthreads();
    int n0 = k * NPB2;
    int ncnt = min(NPB2, N_NODES - n0);
    for (int i = tid; i < ncnt; i += 256) {
        float di = rsqrtf((float)cnt[i] + 1.0f);   // +1 = self loop
        sdi[i] = di;
        dinv[n0 + i] = di;
    }
    __syncthreads();
    for (int g = tid; g < ncnt * 4; g += 256) {    // float4 groups
        int i = g >> 2;
        float di = sdi[i];
        float4* p = (float4*)(h1 + (n0 + i) * D_H);
        float4 v = p[g & 3];
        v.x *= di; v.y *= di; v.z *= di; v.w *= di;
        p[g & 3] = v;
    }
}

// ---- K3: encoder aggregation: zs[i] = di*( di*(h1s_self + S h1s[s]) + b1 )
//      (zs = z*dinv, pre-scaled for the decoder) ----
__global__ __launch_bounds__(1024, 4) void k3_agg_enc(
        const float* __restrict__ feat_s, const int* __restrict__ arr,
        const int* __restrict__ gcur, const float* __restrict__ dinv,
        const float* __restrict__ b1, float* __restrict__ zs) {
    __shared__ __align__(16) float acc[NPB2 * D_H];   // 6.3 KB
    int k = blockIdx.x, tid = threadIdx.x;
    for (int i = tid; i < NPB2 * D_H; i += 1024) acc[i] = 0.0f;
    __syncthreads();
    int count = min(gcur[k * GC_PAD], BCAP);
    int base = k << BSHIFT;
    int ch = tid & 15;
    {
        int i = tid >> 4;                 // 0..63
        for (; i + 192 < count; i += 256) {
            int p0 = arr[base + i];
            int p1 = arr[base + i + 64];
            int p2 = arr[base + i + 128];
            int p3 = arr[base + i + 192];
            float v0 = feat_s[(p0 >> 7) * D_H + ch];
            float v1 = feat_s[(p1 >> 7) * D_H + ch];
            float v2 = feat_s[(p2 >> 7) * D_H + ch];
            float v3 = feat_s[(p3 >> 7) * D_H + ch];
            atomicAdd(&acc[(p0 & 127) * D_H + ch], v0);
            atomicAdd(&acc[(p1 & 127) * D_H + ch], v1);
            atomicAdd(&acc[(p2 & 127) * D_H + ch], v2);
            atomicAdd(&acc[(p3 & 127) * D_H + ch], v3);
        }
        for (; i < count; i += 64) {
            int p = arr[base + i];
            atomicAdd(&acc[(p & 127) * D_H + ch], feat_s[(p >> 7) * D_H + ch]);
        }
    }
    __syncthreads();
    int n0 = k * NPB2;
    int ncnt = min(NPB2, N_NODES - n0);
    for (int idx = tid; idx < ncnt * D_H; idx += 1024) {
        int i = n0 + (idx >> 4);
        int c = idx & 15;
        float di = dinv[i];
        float tot = acc[idx] + feat_s[i * D_H + c];
        zs[i * D_H + c] = di * (di * tot + b1[c]);
    }
}

// ---- K4: decoder aggregation fused with W2 GEMM + b2; writes out directly ----
__global__ __launch_bounds__(1024, 4) void k4_agg_dec_out(
        const float* __restrict__ zs, const int* __restrict__ arr,
        const int* __restrict__ gcur, const float* __restrict__ dinv,
        const float* __restrict__ W2, const float* __restrict__ b2,
        float* __restrict__ out) {
    __shared__ __align__(16) float acc[NPB2 * D_H];   // 6.3 KB
    __shared__ __align__(16) float w2s[D_H * D_IN];   // 8 KB
    int k = blockIdx.x, tid = threadIdx.x;
    for (int i = tid; i < NPB2 * D_H; i += 1024) acc[i] = 0.0f;
    for (int i = tid; i < D_H * D_IN; i += 1024) w2s[i] = W2[i];
    __syncthreads();
    int count = min(gcur[k * GC_PAD], BCAP);
    int base = k << BSHIFT;
    int ch = tid & 15;
    {
        int i = tid >> 4;                 // 0..63
        for (; i + 192 < count; i += 256) {
            int p0 = arr[base + i];
            int p1 = arr[base + i + 64];
            int p2 = arr[base + i + 128];
            int p3 = arr[base + i + 192];
            float v0 = zs[(p0 >> 7) * D_H + ch];
            float v1 = zs[(p1 >> 7) * D_H + ch];
            float v2 = zs[(p2 >> 7) * D_H + ch];
            float v3 = zs[(p3 >> 7) * D_H + ch];
            atomicAdd(&acc[(p0 & 127) * D_H + ch], v0);
            atomicAdd(&acc[(p1 & 127) * D_H + ch], v1);
            atomicAdd(&acc[(p2 & 127) * D_H + ch], v2);
            atomicAdd(&acc[(p3 & 127) * D_H + ch], v3);
        }
        for (; i < count; i += 64) {
            int p = arr[base + i];
            atomicAdd(&acc[(p & 127) * D_H + ch], zs[(p >> 7) * D_H + ch]);
        }
    }
    __syncthreads();
    int n0 = k * NPB2;
    int ncnt = min(NPB2, N_NODES - n0);
    // agg2 in place: acc = di*(acc + zs_self)
    for (int idx = tid; idx < ncnt * D_H; idx += 1024) {
        int i = n0 + (idx >> 4);
        float di = dinv[i];
        acc[idx] = di * (acc[idx] + zs[i * D_H + (idx & 15)]);
    }
    __syncthreads();
    // out[n][j4] = b2[j4] + sum_c acc[n][c]*W2[c][j4]  (float4 over j)
    const float4* w2s4 = (const float4*)w2s;
    const float4* b2_4 = (const float4*)b2;
    for (int g = tid; g < ncnt * (D_IN / 4); g += 1024) {
        int n = g >> 5;
        int j4 = g & 31;
        const float* a = &acc[n * D_H];
        float4 v = b2_4[j4];
        #pragma unroll
        for (int c = 0; c < D_H; ++c) {
            float ac = a[c];
            float4 w = w2s4[c * (D_IN / 4) + j4];
            v.x += ac * w.x; v.y += ac * w.y; v.z += ac * w.z; v.w += ac * w.w;
        }
        ((float4*)(out + (n0 + n) * D_IN))[j4] = v;
    }
}

extern "C" void kernel_launch(void* const* d_in, const int* in_sizes, int n_in,
                              void* d_out, int out_size, void* d_ws, size_t ws_size,
                              hipStream_t stream) {
    const float* x  = (const float*)d_in[0];
    const int*   ei = (const int*)d_in[1];   // [2, E]: src then dst
    const float* W1 = (const float*)d_in[2];
    const float* b1 = (const float*)d_in[3];
    const float* W2 = (const float*)d_in[4];
    const float* b2 = (const float*)d_in[5];
    float* out = (float*)d_out;

    const int* src = ei;
    const int* dst = ei + N_EDGES;

    // ws carve: gcur[512*16] | dinv[N] | h1[N*16] | zs[N*16] | arr[512*2048]  (~10.8 MB)
    char* base = (char*)d_ws;
    int*   gcur = (int*)base;                  base += K_BUCK * GC_PAD * 4;
    float* dinv = (float*)base;                base += N_NODES * 4;
    float* h1   = (float*)base;                base += N_NODES * D_H * 4;
    float* zs   = (float*)base;                base += N_NODES * D_H * 4;
    int*   arr  = (int*)base;                  base += K_BUCK * BCAP * 4;

    hipMemsetAsync(gcur, 0, K_BUCK * GC_PAD * sizeof(int), stream);

    k1_fused<<<PA_BLKS + (N_NODES * D_H / 256), 256, 0, stream>>>(src, dst, x, W1, gcur, h1, arr);
    k2_deg_scale<<<K_BUCK, 256, 0, stream>>>(arr, gcur, h1, dinv);
    k3_agg_enc<<<K_BUCK, 1024, 0, stream>>>(h1, arr, gcur, dinv, b1, zs);
    k4_agg_dec_out<<<K_BUCK, 1024, 0, stream>>>(zs, arr, gcur, dinv, W2, b2, out);
}